// Round 8
// baseline (58.955 us; speedup 1.0000x reference)
//
#include <hip/hip_runtime.h>
#include <stdint.h>

// LearnedTripleConnect: B=8,N=8192,S=8,D=64. out[b,n] = mean_s( gelu([xi|xj|xk]W1+b1) ) W2 + b2
// Round 8: 2 cb per wave (96 VGPR W1, 2 acc chains) + 64-token block-tiles -> halves LDS
// A-read amplification and per-token VALU overhead. Own rows direct-to-reg. setprio on MFMA.

#define NT   8            // 64-token tiles per block
#define NBLK 1024         // 1024*8*64 = 524288 tokens

typedef short  short8 __attribute__((ext_vector_type(8)));
typedef float  f32x4  __attribute__((ext_vector_type(4)));
typedef float  f32x16 __attribute__((ext_vector_type(16)));

__device__ __forceinline__ unsigned short f2bf(float f){
  union { float f; unsigned u; } a; a.f = f;
  unsigned u = a.u;
  u += 0x7fffu + ((u >> 16) & 1u);   // RNE
  return (unsigned short)(u >> 16);
}
__device__ __forceinline__ float fast_gelu(float x){
  // x * sigmoid(1.5957691*(x + 0.044715 x^3)) via exp2; |err vs exact gelu| ~3e-4
  float x2 = x * x;
  float t  = __builtin_fmaf(x2, -0.1029437f, -2.3022083f);
  float p  = __builtin_amdgcn_exp2f(x * t);
  return x * __builtin_amdgcn_rcpf(1.0f + p);
}

// ---------------- fused prep ----------------
__global__ void prep_kernel(const float* __restrict__ x, const float* __restrict__ W1,
                            const float* __restrict__ W2, short* __restrict__ xb,
                            short* __restrict__ w1f, short* __restrict__ w2f){
  int bid = blockIdx.x;
  if (bid < 2048){
    long i = (long)bid * 256 + threadIdx.x;   // 0..524287, 8 elems each
    const float4* p = (const float4*)(x + i * 8);
    float4 a = p[0], b = p[1];
    short8 v;
    v[0]=(short)f2bf(a.x); v[1]=(short)f2bf(a.y); v[2]=(short)f2bf(a.z); v[3]=(short)f2bf(a.w);
    v[4]=(short)f2bf(b.x); v[5]=(short)f2bf(b.y); v[6]=(short)f2bf(b.z); v[7]=(short)f2bf(b.w);
    *(short8*)(xb + i * 8) = v;
  } else if (threadIdx.x < 64){
    int f = bid - 2048, lane = threadIdx.x;
    short8 v;
    if (f < 48){
      int cb = f / 12, t = f % 12;
      #pragma unroll
      for (int j = 0; j < 8; j++)
        v[j] = (short)f2bf(W1[(t*16 + 8*(lane>>5) + j)*128 + cb*32 + (lane&31)]);
      *(short8*)(w1f + ((long)(f*64 + lane))*8) = v;
    } else {
      int g = f - 48; int w = g >> 2, q = g & 3;
      #pragma unroll
      for (int j = 0; j < 8; j++)
        v[j] = (short)f2bf(W2[(q*32 + 8*(lane>>4) + j)*64 + w*16 + (lane&15)]);
      *(short8*)(w2f + ((long)(g*64 + lane))*8) = v;
    }
  }
}

// ---------------- main kernel ----------------
// Block = 4 waves = 2 token-groups (tg) x 2 cb-pairs (q). Wave (tg,q) computes
// C[32 tok of tg][cb=2q..2q+1 (64 h)] with 12 shared A-frags feeding 24 MFMAs.
// LDS Ab per buffer: [tg][j/k][chunk 0..7][tok 0..31] x 16B, chunk-major (conflict-free).
// Own rows loaded direct to regs (4 rows/tg, broadcast).
__global__ __launch_bounds__(256, 2) void ltc_main(
    const short* __restrict__ xb,  const short* __restrict__ w1f,
    const short* __restrict__ w2f, const int* __restrict__ jidx,
    const int* __restrict__ kidx,  const float* __restrict__ b1,
    const float* __restrict__ b2,  float* __restrict__ out)
{
  __shared__ short Ab[2][8192];     // 2 x 16 KB  (tg block 4096 shorts: j 2048 | k 2048)
  __shared__ short HB[2][8 * 136];  // hbar ping-pong: 8 n-rows x 128 h, stride 136

  const int tid  = threadIdx.x;
  const int w    = tid >> 6, lane = tid & 63;
  const int tg   = w >> 1, q = w & 1;           // token-group, cb-pair
  const int l31  = lane & 31, hi = lane >> 5;
  const int l15  = lane & 15, q4 = lane >> 4;

  // resident weight fragments: W1 for cb = 2q and 2q+1 (96 VGPR)
  short8 w1a[12], w1b[12];
  #pragma unroll
  for (int t = 0; t < 12; t++){
    w1a[t] = *(const short8*)(w1f + ((long)(((2*q    ) * 12 + t) * 64 + lane)) * 8);
    w1b[t] = *(const short8*)(w1f + ((long)(((2*q + 1) * 12 + t) * 64 + lane)) * 8);
  }
  short8 w2v[4];                                 // GEMM2 d-tile = w
  #pragma unroll
  for (int q2 = 0; q2 < 4; q2++)
    w2v[q2] = *(const short8*)(w2f + ((long)((w * 4 + q2) * 64 + lane)) * 8);

  const float b1a = b1[(2*q    ) * 32 + l31];
  const float b1b = b1[(2*q + 1) * 32 + l31];
  const float b2v = b2[w * 16 + l15];

  const int bid   = blockIdx.x;
  const int batch = bid & 7;
  const int tile0 = batch * 1024 + (bid >> 3) * NT;   // 64-token tiles, batch-affine XCD swizzle
  const long tb0  = (long)tile0 * 64;
  const int bbase = batch << 13;                      // batch row base (b*8192)

  // GEMM1 j/k read base byte offset within tg block (+= t*1024 per k-step)
  const int oJ = tg * 8192 + hi * 512 + l31 * 16;

  // stage: wave (tg,q) covers tg's j and k chunks {4q+2m+hi : m=0,1}
  auto stage = [&](int buf, int jn, int kn){
    #pragma unroll
    for (int m = 0; m < 2; m++){
      const short* gj = xb + (long)(bbase + jn) * 64 + (4*q + 2*m + hi) * 8;
      __builtin_amdgcn_global_load_lds(
          (const __attribute__((address_space(1))) unsigned int*)gj,
          (__attribute__((address_space(3))) unsigned int*)(&Ab[buf][tg*4096 + (4*q + 2*m)*256]),
          16, 0, 0);
      const short* gk = xb + (long)(bbase + kn) * 64 + (4*q + 2*m + hi) * 8;
      __builtin_amdgcn_global_load_lds(
          (const __attribute__((address_space(1))) unsigned int*)gk,
          (__attribute__((address_space(3))) unsigned int*)(&Ab[buf][tg*4096 + 2048 + (4*q + 2*m)*256]),
          16, 0, 0);
    }
  };

  auto gemm2_store = [&](int hb, int ttp){
    f32x4 acc2 = {0.f, 0.f, 0.f, 0.f};
    #pragma unroll
    for (int q2 = 0; q2 < 4; q2++){
      // A-frag: hbar[row l15&7][k = 32q2 + 8q4 + j]
      short8 hbf = *(const short8*)((const char*)&HB[hb][0] + (l15 & 7) * 272 + q2 * 64 + q4 * 16);
      acc2 = __builtin_amdgcn_mfma_f32_16x16x32_bf16(hbf, w2v[q2], acc2, 0, 0, 0);
    }
    if (lane < 32){                       // C rows 0-7 = the 8 valid n
      long Gn = ((long)(tile0 + ttp)) * 8;
      #pragma unroll
      for (int r = 0; r < 4; r++)
        out[(Gn + 4 * q4 + r) * 64 + w * 16 + l15] = acc2[r] + b2v;
    }
  };

  // prologue
  int jn = jidx[tb0 + tg * 32 + l31], kn = kidx[tb0 + tg * 32 + l31];
  stage(0, jn, kn);
  int jnS = 0, knS = 0;
  if (NT > 1){ jnS = jidx[tb0 + 64 + tg * 32 + l31]; knS = kidx[tb0 + 64 + tg * 32 + l31]; }

  for (int tt = 0; tt < NT; ++tt){
    const int cur = tt & 1;
    asm volatile("s_waitcnt vmcnt(0) lgkmcnt(0)\n\ts_barrier" ::: "memory");  // Ab[cur]+HB[cur^1] ready
    if (tt + 1 < NT) stage(cur ^ 1, jnS, knS);

    // own rows direct to regs (4 rows per tg, 8-lane broadcast), issued early
    long tb = tb0 + (long)tt * 64;
    int own = (int)(tb >> 3) + tg * 4 + (l31 >> 3);
    short8 afo[4];
    #pragma unroll
    for (int t2 = 0; t2 < 4; t2++)
      afo[t2] = *(const short8*)(xb + (long)own * 64 + (2*t2 + hi) * 8);

    if (tt + 2 < NT){
      jnS = jidx[tb0 + (long)(tt + 2) * 64 + tg * 32 + l31];
      knS = kidx[tb0 + (long)(tt + 2) * 64 + tg * 32 + l31];
    }

    // deferred GEMM2 of previous tile (HB published by this tile's top barrier)
    if (tt > 0) gemm2_store((tt ^ 1) & 1, tt - 1);

    // GEMM1: two C[32 tok][32 h] quadrants (cb = 2q, 2q+1), shared A-frags
    const char* Abase = (const char*)&Ab[cur][0];
    f32x16 accA, accB;
    #pragma unroll
    for (int r = 0; r < 16; r++){ accA[r] = b1a; accB[r] = b1b; }
    __builtin_amdgcn_s_setprio(1);
    #pragma unroll
    for (int t = 0; t < 4; t++){
      accA = __builtin_amdgcn_mfma_f32_32x32x16_bf16(afo[t], w1a[t], accA, 0, 0, 0);
      accB = __builtin_amdgcn_mfma_f32_32x32x16_bf16(afo[t], w1b[t], accB, 0, 0, 0);
    }
    #pragma unroll
    for (int t = 4; t < 8; t++){
      short8 af = *(const short8*)(Abase + oJ + (t - 4) * 1024);
      accA = __builtin_amdgcn_mfma_f32_32x32x16_bf16(af, w1a[t], accA, 0, 0, 0);
      accB = __builtin_amdgcn_mfma_f32_32x32x16_bf16(af, w1b[t], accB, 0, 0, 0);
    }
    #pragma unroll
    for (int t = 8; t < 12; t++){
      short8 af = *(const short8*)(Abase + oJ + 4096 + (t - 8) * 1024);
      accA = __builtin_amdgcn_mfma_f32_32x32x16_bf16(af, w1a[t], accA, 0, 0, 0);
      accB = __builtin_amdgcn_mfma_f32_32x32x16_bf16(af, w1b[t], accB, 0, 0, 0);
    }
    __builtin_amdgcn_s_setprio(0);

    // GELU + s-reduce: token row=(reg&3)+8*(reg>>2)+4*hi -> n-local o=reg>>2, s=(reg&3)+4*hi
    #pragma unroll
    for (int o = 0; o < 4; o++){
      float sA = fast_gelu(accA[4*o+0]);
      sA += fast_gelu(accA[4*o+1]);
      sA += fast_gelu(accA[4*o+2]);
      sA += fast_gelu(accA[4*o+3]);
      float sB = fast_gelu(accB[4*o+0]);
      sB += fast_gelu(accB[4*o+1]);
      sB += fast_gelu(accB[4*o+2]);
      sB += fast_gelu(accB[4*o+3]);
      float oA = __shfl_xor(sA, 32);
      float oB = __shfl_xor(sB, 32);
      float hA = (sA + oA) * 0.125f;
      float hB = (sB + oB) * 0.125f;
      if (hi == 0){
        HB[cur][(tg * 4 + o) * 136 + (2*q    ) * 32 + l31] = (short)f2bf(hA);
        HB[cur][(tg * 4 + o) * 136 + (2*q + 1) * 32 + l31] = (short)f2bf(hB);
      }
    }
  }

  // epilogue: last tile's GEMM2
  asm volatile("s_waitcnt lgkmcnt(0)\n\ts_barrier" ::: "memory");
  gemm2_store((NT - 1) & 1, NT - 1);
}

// ---------------- fallback (ws too small): correct, slow ----------------
__global__ void ltc_naive(const float* __restrict__ x, const int* __restrict__ jidx,
                          const int* __restrict__ kidx, const float* __restrict__ W1,
                          const float* __restrict__ b1, const float* __restrict__ W2,
                          const float* __restrict__ b2, float* __restrict__ out)
{
  int gidx = blockIdx.x;            // b*8192+n
  int b = gidx >> 13;
  __shared__ float trip[8][192];
  __shared__ float hb[128];
  int t = threadIdx.x;              // 128
  for (int i = t; i < 8 * 192; i += 128){
    int s = i / 192, c = i - s * 192;
    int v = c >> 6, cc = c & 63;
    int src;
    if (v == 0)      src = gidx & 8191;
    else if (v == 1) src = jidx[gidx * 8 + s];
    else             src = kidx[gidx * 8 + s];
    trip[s][c] = x[((long)(b << 13) + src) * 64 + cc];
  }
  __syncthreads();
  float z[8];
  #pragma unroll
  for (int s = 0; s < 8; s++) z[s] = b1[t];
  for (int k = 0; k < 192; k++){
    float wv = W1[k * 128 + t];
    #pragma unroll
    for (int s = 0; s < 8; s++) z[s] = fmaf(trip[s][k], wv, z[s]);
  }
  float acc = 0.f;
  #pragma unroll
  for (int s = 0; s < 8; s++) acc += fast_gelu(z[s]);
  hb[t] = acc * 0.125f;
  __syncthreads();
  if (t < 64){
    float o = b2[t];
    for (int h = 0; h < 128; h++) o = fmaf(hb[h], W2[h * 64 + t], o);
    out[(long)gidx * 64 + t] = o;
  }
}

extern "C" void kernel_launch(void* const* d_in, const int* in_sizes, int n_in,
                              void* d_out, int out_size, void* d_ws, size_t ws_size,
                              hipStream_t stream) {
  const float* x   = (const float*)d_in[0];
  const int*   jix = (const int*)  d_in[1];
  const int*   kix = (const int*)  d_in[2];
  const float* W1  = (const float*)d_in[3];
  const float* b1  = (const float*)d_in[4];
  const float* W2  = (const float*)d_in[5];
  const float* b2  = (const float*)d_in[6];
  float* out = (float*)d_out;

  const size_t xb_elems  = (size_t)8 * 8192 * 64;        // 4,194,304 bf16
  const size_t w1f_elems = 48 * 64 * 8;
  const size_t w2f_elems = 16 * 64 * 8;
  const size_t need = (xb_elems + w1f_elems + w2f_elems) * sizeof(short);

  if (ws_size >= need){
    short* xb  = (short*)d_ws;
    short* w1f = xb + xb_elems;
    short* w2f = w1f + w1f_elems;
    prep_kernel<<<2112, 256, 0, stream>>>(x, W1, W2, xb, w1f, w2f);
    ltc_main<<<NBLK, 256, 0, stream>>>(xb, w1f, w2f, jix, kix, b1, b2, out);
  } else {
    ltc_naive<<<8 * 8192, 128, 0, stream>>>(x, jix, kix, W1, b1, W2, b2, out);
  }
}